// Round 5
// baseline (965.821 us; speedup 1.0000x reference)
//
#include <hip/hip_runtime.h>
#include <hip/hip_fp16.h>
#include <math.h>

#define T_STEPS 8
#define F_IN    8
#define HID     32
#define KCH     5
#define PERIODS 8

__device__ __forceinline__ float sigmoidf_(float x) { return 1.f / (1.f + __expf(-x)); }
__device__ __forceinline__ float tanhf_(float x) {
    float e = __expf(2.f * x);
    return 1.f - 2.f / (e + 1.f);
}

// ---------------- graph setup ----------------

// degi: out-degree by src (for normalization); cnt: in-degree by dst (CSR rows)
__global__ void k_count(const int* __restrict__ src, const int* __restrict__ dst,
                        int* __restrict__ degi, int* __restrict__ cnt, int E) {
    int e = blockIdx.x * blockDim.x + threadIdx.x;
    if (e >= E) return;
    int s = src[e], d = dst[e];
    if (s != d) {
        atomicAdd(&degi[s], 1);
        atomicAdd(&cnt[d], 1);
    }
}

__global__ void k_dis(const int* __restrict__ degi, float* __restrict__ dis, int N) {
    int n = blockIdx.x * blockDim.x + threadIdx.x;
    if (n >= N) return;
    int d = degi[n];
    dis[n] = (d > 0) ? rsqrtf((float)d) : 0.f;
}

// exclusive scan of cnt[0..N) -> row_ptr[0..N]. Single block, 1024 threads,
// 32 elems/thread, 2 barriers. Valid for N <= 32768.
__global__ void __launch_bounds__(1024) k_scan(const int* __restrict__ cnt,
                                               int* __restrict__ row_ptr, int N) {
    __shared__ int wsum[16];
    int tid = threadIdx.x;
    int base = tid * 32;
    int v[32];
    int s = 0;
    #pragma unroll
    for (int i = 0; i < 32; ++i) {
        int idx = base + i;
        int t = (idx < N) ? cnt[idx] : 0;
        v[i] = t; s += t;
    }
    int lane = tid & 63, wave = tid >> 6;
    int incl = s;
    #pragma unroll
    for (int off = 1; off < 64; off <<= 1) {
        int t = __shfl_up(incl, off, 64);
        if (lane >= off) incl += t;
    }
    if (lane == 63) wsum[wave] = incl;
    __syncthreads();
    if (tid < 64) {
        int w = (tid < 16) ? wsum[tid] : 0;
        int iw = w;
        #pragma unroll
        for (int off = 1; off < 16; off <<= 1) {
            int t = __shfl_up(iw, off, 64);
            if (tid >= off) iw += t;
        }
        if (tid < 16) wsum[tid] = iw - w;
    }
    __syncthreads();
    int excl = wsum[wave] + (incl - s);
    #pragma unroll
    for (int i = 0; i < 32; ++i) {
        int idx = base + i;
        if (idx < N) row_ptr[idx] = excl;
        excl += v[i];
    }
    if (tid == 1023) row_ptr[N] = wsum[15] + incl;
}

// degree histogram (key = in-degree, clamped to 1023)
__global__ void k_hist(const int* __restrict__ cnt, int* __restrict__ hist, int N) {
    int n = blockIdx.x * blockDim.x + threadIdx.x;
    if (n >= N) return;
    atomicAdd(&hist[min(cnt[n], 1023)], 1);
}

// counting-sort scatter: perm[pos] = orig node, iperm[orig] = pos
__global__ void k_permscat(const int* __restrict__ cnt, const int* __restrict__ hbase,
                           int* __restrict__ hfill, int* __restrict__ perm,
                           int* __restrict__ iperm, int N) {
    int n = blockIdx.x * blockDim.x + threadIdx.x;
    if (n >= N) return;
    int key = min(cnt[n], 1023);
    int pos = hbase[key] + atomicAdd(&hfill[key], 1);
    perm[pos] = n;
    iperm[n] = pos;
}

__global__ void k_cntp(const int* __restrict__ cnt, const int* __restrict__ perm,
                       int* __restrict__ cntp, int N) {
    int i = blockIdx.x * blockDim.x + threadIdx.x;
    if (i >= N) return;
    cntp[i] = cnt[perm[i]];
}

// edge scatter into permuted CSR; packs (permuted col, -norm)
__global__ void k_scatter(const int* __restrict__ src, const int* __restrict__ dst,
                          const float* __restrict__ dis, const int* __restrict__ rowptr,
                          const int* __restrict__ iperm, int* __restrict__ fill,
                          int2* __restrict__ cv, int E) {
    int e = blockIdx.x * blockDim.x + threadIdx.x;
    if (e >= E) return;
    int s = src[e], d = dst[e];
    if (s == d) return;
    float nv = -dis[s] * dis[d];
    int dp = iperm[d];
    int p = atomicAdd(&fill[dp], 1);
    cv[rowptr[dp] + p] = make_int2(iperm[s], __float_as_int(nv));
}

// transpose + permute + fp16-pack x: [T][N][8] f32 -> xb [Np][64] half
__global__ void k_xt(const float* __restrict__ xall, const int* __restrict__ iperm,
                     __half* __restrict__ xb, int N) {
    int i = blockIdx.x * blockDim.x + threadIdx.x;
    if (i >= N * T_STEPS) return;
    int n = i >> 3, t = i & 7;
    float4 a = *(const float4*)(xall + ((size_t)t * N + n) * 8);
    float4 b = *(const float4*)(xall + ((size_t)t * N + n) * 8 + 4);
    __half2 h[4];
    h[0] = __float22half2_rn(make_float2(a.x, a.y));
    h[1] = __float22half2_rn(make_float2(a.z, a.w));
    h[2] = __float22half2_rn(make_float2(b.x, b.y));
    h[3] = __float22half2_rn(make_float2(b.z, b.w));
    *(float4*)(xb + (size_t)iperm[n] * 64 + t * 8) = *(float4*)h;
}

// ---------------- Laplacian (pull, permuted CSR, fp16 features) ----------------
// out[n][c] = alpha * sum_j val[j]*xin[col[j]][c] + beta * xprev[n][c]
// C in half-elements; each lane handles 8 halves (16 B).
template <int C>
__global__ void __launch_bounds__(256) k_lap_h(__half* __restrict__ outp,
                                               const __half* __restrict__ xin,
                                               const __half* __restrict__ xprev,
                                               float alpha, float beta,
                                               const int* __restrict__ rowptr,
                                               const int2* __restrict__ cv, int N) {
    constexpr int Q = C / 8;
    int idx = blockIdx.x * 256 + threadIdx.x;
    int node = idx / Q, q = idx % Q;
    if (node >= N) return;
    int beg = rowptr[node], end = rowptr[node + 1];
    float a0 = 0.f, a1 = 0.f, a2 = 0.f, a3 = 0.f, a4 = 0.f, a5 = 0.f, a6 = 0.f, a7 = 0.f;
    #pragma unroll 4
    for (int j = beg; j < end; ++j) {
        int2 p = cv[j];
        float nv = __int_as_float(p.y);
        float4 raw = *(const float4*)(xin + (size_t)p.x * C + q * 8);
        const __half2* h = (const __half2*)&raw;
        float2 f0 = __half22float2(h[0]);
        float2 f1 = __half22float2(h[1]);
        float2 f2 = __half22float2(h[2]);
        float2 f3 = __half22float2(h[3]);
        a0 += nv * f0.x; a1 += nv * f0.y; a2 += nv * f1.x; a3 += nv * f1.y;
        a4 += nv * f2.x; a5 += nv * f2.y; a6 += nv * f3.x; a7 += nv * f3.y;
    }
    size_t off = (size_t)node * C + q * 8;
    float r0 = alpha * a0, r1 = alpha * a1, r2 = alpha * a2, r3 = alpha * a3;
    float r4 = alpha * a4, r5 = alpha * a5, r6 = alpha * a6, r7 = alpha * a7;
    if (beta != 0.f) {
        float4 raw = *(const float4*)(xprev + off);
        const __half2* h = (const __half2*)&raw;
        float2 f0 = __half22float2(h[0]);
        float2 f1 = __half22float2(h[1]);
        float2 f2 = __half22float2(h[2]);
        float2 f3 = __half22float2(h[3]);
        r0 += beta * f0.x; r1 += beta * f0.y; r2 += beta * f1.x; r3 += beta * f1.y;
        r4 += beta * f2.x; r5 += beta * f2.y; r6 += beta * f3.x; r7 += beta * f3.y;
    }
    __half2 o[4];
    o[0] = __float22half2_rn(make_float2(r0, r1));
    o[1] = __float22half2_rn(make_float2(r2, r3));
    o[2] = __float22half2_rn(make_float2(r4, r5));
    o[3] = __float22half2_rn(make_float2(r6, r7));
    *(float4*)(outp + off) = *(float4*)o;
}

// ---------------- fused gate GEMM + LSTM pointwise (register-blocked) --------
// 64 nodes/block, 256 threads = 16 output-groups x 16 node-groups.
// Thread tile: 4 nodes x 8 outputs; output axis permuted to o' = h*4+g so the
// LSTM pointwise is register-local. fp16 feature staging, fp32 math.
#define NB   64
#define WSLD 140
#define TSLD 68

__global__ void __launch_bounds__(256) k_step(
    const __half* __restrict__ xb,    // [N][64]
    const __half* __restrict__ TXB,   // [4][N][64]
    __half* __restrict__ THall,       // [5][N][32]  slice 0 = H (in/out)
    float* __restrict__ Cst,          // [N][32] fp32
    const float* __restrict__ Wx,     // [4][5][8][32]
    const float* __restrict__ Wh,     // [4][5][32][32]
    const float* __restrict__ w_c,    // [3][32]
    const float* __restrict__ bg,     // [4][32]
    int t, int N) {
    __shared__ float Ws[40 * WSLD];
    __shared__ float Ts[40 * TSLD];
    int tid = threadIdx.x;
    int base = blockIdx.x * NB;
    int og = tid & 15;
    int o0 = og * 8;
    int h0 = og * 2;
    int n0 = (tid >> 4) * 4;
    int wp0 = o0 + 4 * (o0 >> 5);

    float acc[4][8];
    #pragma unroll
    for (int oj = 0; oj < 8; ++oj) {
        float b = bg[(oj & 3) * 32 + h0 + (oj >> 2)];
        #pragma unroll
        for (int nj = 0; nj < 4; ++nj) acc[nj][oj] = b;
    }

    // ---- chunk 0: x-terms (40 rows = 5 k x 8 ch) ----
    for (int i = tid; i < 40 * 128; i += 256) {
        int ci = i >> 7, o = i & 127;
        int k = ci >> 3, c = ci & 7, h = o >> 2, g = o & 3;
        Ws[ci * WSLD + o + 4 * (o >> 5)] = Wx[(((g * KCH + k) * 8) + c) * 32 + h];
    }
    for (int i = tid; i < NB * 5; i += 256) {
        int nl = i / 5, k = i % 5;
        int node = base + nl; if (node >= N) node = N - 1;
        const __half* sp = (k == 0) ? (xb + (size_t)node * 64 + t * 8)
                                    : (TXB + ((size_t)(k - 1) * N + node) * 64 + t * 8);
        float4 raw = *(const float4*)sp;
        const __half2* h = (const __half2*)&raw;
        float2 f0 = __half22float2(h[0]);
        float2 f1 = __half22float2(h[1]);
        float2 f2 = __half22float2(h[2]);
        float2 f3 = __half22float2(h[3]);
        int row = k * 8;
        Ts[(row + 0) * TSLD + nl] = f0.x; Ts[(row + 1) * TSLD + nl] = f0.y;
        Ts[(row + 2) * TSLD + nl] = f1.x; Ts[(row + 3) * TSLD + nl] = f1.y;
        Ts[(row + 4) * TSLD + nl] = f2.x; Ts[(row + 5) * TSLD + nl] = f2.y;
        Ts[(row + 6) * TSLD + nl] = f3.x; Ts[(row + 7) * TSLD + nl] = f3.y;
    }
    __syncthreads();
    #pragma unroll 4
    for (int c = 0; c < 40; ++c) {
        float4 wA = *(const float4*)(Ws + c * WSLD + wp0);
        float4 wB = *(const float4*)(Ws + c * WSLD + wp0 + 4);
        float4 tA = *(const float4*)(Ts + c * TSLD + n0);
        float wv[8] = {wA.x, wA.y, wA.z, wA.w, wB.x, wB.y, wB.z, wB.w};
        float tv[4] = {tA.x, tA.y, tA.z, tA.w};
        #pragma unroll
        for (int nj = 0; nj < 4; ++nj)
            #pragma unroll
            for (int oj = 0; oj < 8; ++oj)
                acc[nj][oj] += tv[nj] * wv[oj];
    }

    // ---- chunks 1..5: H-terms k=0..4 (32 rows each) ----
    for (int k = 0; k < KCH; ++k) {
        __syncthreads();
        for (int i = tid; i < 32 * 128; i += 256) {
            int ci = i >> 7, o = i & 127;
            int h = o >> 2, g = o & 3;
            Ws[ci * WSLD + o + 4 * (o >> 5)] = Wh[(((g * KCH + k) * 32) + ci) * 32 + h];
        }
        for (int i = tid; i < NB * 4; i += 256) {
            int nl = i >> 2, qq = i & 3;
            int node = base + nl; if (node >= N) node = N - 1;
            float4 raw = *(const float4*)(THall + ((size_t)k * N + node) * 32 + qq * 8);
            const __half2* h = (const __half2*)&raw;
            float2 f0 = __half22float2(h[0]);
            float2 f1 = __half22float2(h[1]);
            float2 f2 = __half22float2(h[2]);
            float2 f3 = __half22float2(h[3]);
            int row = qq * 8;
            Ts[(row + 0) * TSLD + nl] = f0.x; Ts[(row + 1) * TSLD + nl] = f0.y;
            Ts[(row + 2) * TSLD + nl] = f1.x; Ts[(row + 3) * TSLD + nl] = f1.y;
            Ts[(row + 4) * TSLD + nl] = f2.x; Ts[(row + 5) * TSLD + nl] = f2.y;
            Ts[(row + 6) * TSLD + nl] = f3.x; Ts[(row + 7) * TSLD + nl] = f3.y;
        }
        __syncthreads();
        #pragma unroll 4
        for (int c = 0; c < 32; ++c) {
            float4 wA = *(const float4*)(Ws + c * WSLD + wp0);
            float4 wB = *(const float4*)(Ws + c * WSLD + wp0 + 4);
            float4 tA = *(const float4*)(Ts + c * TSLD + n0);
            float wv[8] = {wA.x, wA.y, wA.z, wA.w, wB.x, wB.y, wB.z, wB.w};
            float tv[4] = {tA.x, tA.y, tA.z, tA.w};
            #pragma unroll
            for (int nj = 0; nj < 4; ++nj)
                #pragma unroll
                for (int oj = 0; oj < 8; ++oj)
                    acc[nj][oj] += tv[nj] * wv[oj];
        }
    }

    // ---- LSTM pointwise, register-local ----
    float wci0 = w_c[h0],      wci1 = w_c[h0 + 1];
    float wcf0 = w_c[32 + h0], wcf1 = w_c[32 + h0 + 1];
    float wco0 = w_c[64 + h0], wco1 = w_c[64 + h0 + 1];
    #pragma unroll
    for (int nj = 0; nj < 4; ++nj) {
        int node = base + n0 + nj;
        if (node < N) {
            size_t idx = (size_t)node * 32 + h0;
            float2 Co = *(const float2*)(Cst + idx);
            float2 Cn2, Hn;
            {
                float I  = sigmoidf_(acc[nj][0] + wci0 * Co.x);
                float F  = sigmoidf_(acc[nj][1] + wcf0 * Co.x);
                float Tg = tanhf_(acc[nj][2]);
                float Cn = F * Co.x + I * Tg;
                float O  = sigmoidf_(acc[nj][3] + wco0 * Cn);
                Cn2.x = Cn; Hn.x = O * tanhf_(Cn);
            }
            {
                float I  = sigmoidf_(acc[nj][4] + wci1 * Co.y);
                float F  = sigmoidf_(acc[nj][5] + wcf1 * Co.y);
                float Tg = tanhf_(acc[nj][6]);
                float Cn = F * Co.y + I * Tg;
                float O  = sigmoidf_(acc[nj][7] + wco1 * Cn);
                Cn2.y = Cn; Hn.y = O * tanhf_(Cn);
            }
            *(float2*)(Cst + idx) = Cn2;
            *(__half2*)(THall + idx) = __float22half2_rn(make_float2(Hn.x, Hn.y));
        }
    }
}

// out[perm[i]][p] = sum_h relu(H[i][h]) * W_lin[p][h] + b_lin[p]
__global__ void k_out(const __half* __restrict__ H, const float* __restrict__ W_lin,
                      const float* __restrict__ b_lin, const int* __restrict__ perm,
                      float* __restrict__ out, int N) {
    int idx = blockIdx.x * blockDim.x + threadIdx.x;
    if (idx >= N * PERIODS) return;
    int i = idx / PERIODS, p = idx % PERIODS;
    float acc = b_lin[p];
    const __half* Hp = H + (size_t)i * HID;
    #pragma unroll
    for (int h = 0; h < HID; ++h)
        acc += fmaxf(__half2float(Hp[h]), 0.f) * W_lin[p * HID + h];
    out[(size_t)perm[i] * PERIODS + p] = acc;
}

// ---------------- launch ----------------

extern "C" void kernel_launch(void* const* d_in, const int* in_sizes, int n_in,
                              void* d_out, int out_size, void* d_ws, size_t ws_size,
                              hipStream_t stream) {
    const float* xall  = (const float*)d_in[0];
    const int*   ei    = (const int*)d_in[1];
    const float* Wx    = (const float*)d_in[2];
    const float* Wh    = (const float*)d_in[3];
    const float* w_c   = (const float*)d_in[4];
    const float* bg    = (const float*)d_in[5];
    const float* W_lin = (const float*)d_in[6];
    const float* b_lin = (const float*)d_in[7];
    float* out = (float*)d_out;

    const int E = in_sizes[1] / 2;
    const int N = in_sizes[0] / (T_STEPS * F_IN);
    const int* src = ei;
    const int* dst = ei + E;

    char* p = (char*)d_ws;
    auto carve = [&](size_t bytes) -> void* {
        void* r = (void*)p;
        p += (bytes + 255) & ~(size_t)255;
        return r;
    };
    // zero block: degi, cnt, fill, hist, hfill, Cst, THall slice 0 (= H0)
    char* zero_begin = p;
    int*    degi  = (int*)   carve((size_t)N * 4);
    int*    cnt   = (int*)   carve((size_t)N * 4);
    int*    fill  = (int*)   carve((size_t)N * 4);
    int*    hist  = (int*)   carve(1024 * 4);
    int*    hfill = (int*)   carve(1024 * 4);
    float*  Cst   = (float*) carve((size_t)N * HID * 4);
    __half* THall = (__half*)carve((size_t)KCH * N * HID * 2);
    size_t zero_bytes = (size_t)((char*)THall - zero_begin) + (size_t)N * HID * 2;
    float*  dis    = (float*) carve((size_t)N * 4);
    int*    hbase  = (int*)   carve(1025 * 4);
    int*    perm   = (int*)   carve((size_t)N * 4);
    int*    iperm  = (int*)   carve((size_t)N * 4);
    int*    cntp   = (int*)   carve((size_t)N * 4);
    int*    rowptr = (int*)   carve((size_t)(N + 1) * 4);
    int2*   cv     = (int2*)  carve((size_t)E * 8);
    __half* xb     = (__half*)carve((size_t)N * 64 * 2);
    __half* TXB    = (__half*)carve((size_t)4 * N * 64 * 2);

    hipMemsetAsync(zero_begin, 0, zero_bytes, stream);

    const int TB = 256;
    const int gN = (N + TB - 1) / TB;
    const int gE = (E + TB - 1) / TB;
    k_count<<<gE, TB, 0, stream>>>(src, dst, degi, cnt, E);
    k_dis<<<gN, TB, 0, stream>>>(degi, dis, N);
    k_hist<<<gN, TB, 0, stream>>>(cnt, hist, N);
    k_scan<<<1, 1024, 0, stream>>>(hist, hbase, 1024);
    k_permscat<<<gN, TB, 0, stream>>>(cnt, hbase, hfill, perm, iperm, N);
    k_cntp<<<gN, TB, 0, stream>>>(cnt, perm, cntp, N);
    k_scan<<<1, 1024, 0, stream>>>(cntp, rowptr, N);
    k_scatter<<<gE, TB, 0, stream>>>(src, dst, dis, rowptr, iperm, fill, cv, E);
    k_xt<<<(N * T_STEPS + TB - 1) / TB, TB, 0, stream>>>(xall, iperm, xb, N);

    // batched x-phase Chebyshev terms over all timesteps (C = 64 halves)
    __half* TXB0 = TXB;
    __half* TXB1 = TXB + (size_t)N * 64;
    __half* TXB2 = TXB + (size_t)2 * N * 64;
    __half* TXB3 = TXB + (size_t)3 * N * 64;
    const int lapx_grid = (N * 8 + TB - 1) / TB;   // Q=8
    k_lap_h<64><<<lapx_grid, TB, 0, stream>>>(TXB0, xb,   nullptr, 1.f,  0.f, rowptr, cv, N);
    k_lap_h<64><<<lapx_grid, TB, 0, stream>>>(TXB1, TXB0, xb,      2.f, -1.f, rowptr, cv, N);
    k_lap_h<64><<<lapx_grid, TB, 0, stream>>>(TXB2, TXB1, TXB0,    2.f, -1.f, rowptr, cv, N);
    k_lap_h<64><<<lapx_grid, TB, 0, stream>>>(TXB3, TXB2, TXB1,    2.f, -1.f, rowptr, cv, N);

    const int laph_grid = (N * 4 + TB - 1) / TB;   // Q=4
    const int step_grid = (N + NB - 1) / NB;
    __half* TH0 = THall;
    __half* TH1 = THall + (size_t)N * HID;
    __half* TH2 = THall + (size_t)2 * N * HID;
    __half* TH3 = THall + (size_t)3 * N * HID;
    __half* TH4 = THall + (size_t)4 * N * HID;

    for (int t = 0; t < T_STEPS; ++t) {
        k_lap_h<HID><<<laph_grid, TB, 0, stream>>>(TH1, TH0, nullptr, 1.f,  0.f, rowptr, cv, N);
        k_lap_h<HID><<<laph_grid, TB, 0, stream>>>(TH2, TH1, TH0,     2.f, -1.f, rowptr, cv, N);
        k_lap_h<HID><<<laph_grid, TB, 0, stream>>>(TH3, TH2, TH1,     2.f, -1.f, rowptr, cv, N);
        k_lap_h<HID><<<laph_grid, TB, 0, stream>>>(TH4, TH3, TH2,     2.f, -1.f, rowptr, cv, N);
        k_step<<<step_grid, TB, 0, stream>>>(xb, TXB, THall, Cst, Wx, Wh, w_c, bg, t, N);
    }

    k_out<<<(N * PERIODS + TB - 1) / TB, TB, 0, stream>>>(TH0, W_lin, b_lin, perm, out, N);
}